// Round 1
// 214.708 us; speedup vs baseline: 1.1280x; 1.1280x over previous
//
#include <hip/hip_runtime.h>
#include <math.h>

// Problem constants (fixed by setup_inputs)
#define N_NODES 1024
#define F_DIM   1024
#define H_DIM   512
#define E_EDGES 32768
#define B_GRAPHS 16
#define OUT_DIM 10
#define FH_DIM  1536
#define EPS 1e-5f
#define MH_C_D 0.8673250705840776
#define C2_D   0.72134752044448170368   // 0.5*log2(e)
#define CSC    0.84932180028801904272f  // sqrt(C2)
#define WC2F   ((float)(MH_C_D / C2_D)) // MH_C / C2
#define INV_SQRT2 0.70710678118654752440f

typedef float v2f __attribute__((ext_vector_type(2)));
typedef unsigned int u32;
typedef const __attribute__((address_space(1))) u32 gu32;
typedef __attribute__((address_space(3))) u32 lu32;

#if __has_builtin(__builtin_amdgcn_exp2f)
#define EXP2NEG(x) __builtin_amdgcn_exp2f(-(x))   // exp2(-x), neg is free src modifier
#else
#define EXP2NEG(x) __expf(-0.69314718055994530942f * (x))
#endif

// ---------------- K1: Haar split + attention gate -> h ----------------
__global__ __launch_bounds__(256) void k_h(const float* __restrict__ x,
                                           const float* __restrict__ watt,
                                           float* __restrict__ h) {
    int idx = blockIdx.x * 256 + threadIdx.x;          // 0 .. N*H-1
    float2 p = ((const float2*)x)[idx];
    float lo = (p.x + p.y) * INV_SQRT2;
    float hi = (p.x - p.y) * INV_SQRT2;
    float t  = lo * watt[0] + hi * watt[1];
    float sc = 1.0f / (1.0f + __expf(-t));
    h[idx] = sc * lo + (1.0f - sc) * hi;
}

// ---------------- zero stats + deg ----------------
__global__ __launch_bounds__(256) void k_zero(float* __restrict__ p) {
    p[blockIdx.x * 256 + threadIdx.x] = 0.0f;
}

// ---------------- edge bucketing (counting sort by dst) ----------------
__global__ __launch_bounds__(256) void k_hist(const int* __restrict__ dst,
                                              int* __restrict__ deg) {
    int e = blockIdx.x * 256 + threadIdx.x;
    atomicAdd(&deg[dst[e]], 1);
}

// shfl-based scan: per-wave inclusive scan + cross-wave fixup (2 barriers vs 20)
__global__ __launch_bounds__(1024) void k_scan(const int* __restrict__ deg,
                                               int* __restrict__ start,
                                               int* __restrict__ cursor) {
    __shared__ int wsum[16];
    int t = threadIdx.x;
    int lane = t & 63, wid = t >> 6;
    int v = deg[t];
    int x = v;
    #pragma unroll
    for (int off = 1; off < 64; off <<= 1) {
        int y = __shfl_up(x, off, 64);
        if (lane >= off) x += y;
    }
    if (lane == 63) wsum[wid] = x;
    __syncthreads();
    if (t < 16) {
        int w = wsum[t];
        int xs = w;
        #pragma unroll
        for (int off = 1; off < 16; off <<= 1) {
            int y = __shfl_up(xs, off, 64);
            if (t >= off) xs += y;
        }
        wsum[t] = xs - w;   // exclusive prefix of wave sums
    }
    __syncthreads();
    int excl = wsum[wid] + x - v;
    start[t] = excl;
    cursor[t] = excl;
}

__global__ __launch_bounds__(256) void k_fill(const int* __restrict__ src,
                                              const int* __restrict__ dst,
                                              int* __restrict__ cursor,
                                              int* __restrict__ elist) {
    int e = blockIdx.x * 256 + threadIdx.x;
    int slot = atomicAdd(&cursor[dst[e]], 1);
    elist[slot] = src[e];
}

// ---------------- K2: gather (atomic-free scatter-add), float2 + unroll2 ----------------
__global__ __launch_bounds__(256) void k_gather(const float* __restrict__ h,
                                                const int* __restrict__ start,
                                                const int* __restrict__ deg,
                                                const int* __restrict__ elist,
                                                float* __restrict__ agg) {
    int d = blockIdx.x;
    int t = threadIdx.x;
    int st = start[d], dg = deg[d];
    const float2* h2 = (const float2*)h;
    float2 a = h2[d * 256 + t];
    int k = 0;
    for (; k + 2 <= dg; k += 2) {
        int s0 = elist[st + k];
        int s1 = elist[st + k + 1];
        float2 v0 = h2[s0 * 256 + t];
        float2 v1 = h2[s1 * 256 + t];
        a.x += v0.x + v1.x;
        a.y += v0.y + v1.y;
    }
    if (k < dg) {
        int s0 = elist[st + k];
        float2 v0 = h2[s0 * 256 + t];
        a.x += v0.x; a.y += v0.y;
    }
    ((float2*)agg)[d * 256 + t] = a;
}

// ---------------- K2b: transpose agg [n][i] -> aggT [i][n], + siluT ----------------
__global__ __launch_bounds__(256) void k_transpose(const float* __restrict__ agg,
                                                   float* __restrict__ aggT,
                                                   float* __restrict__ siluT) {
    __shared__ float tile[64 * 65];
    const int t = threadIdx.x;
    const int n0 = blockIdx.x * 64;
    const int i0 = blockIdx.y * 64;
    #pragma unroll
    for (int v = 0; v < 4; ++v) {
        int flat = v * 256 + t;
        int r = flat >> 4, c4 = flat & 15;
        float4 a = *(const float4*)&agg[(n0 + r) * H_DIM + i0 + c4 * 4];
        tile[(c4 * 4 + 0) * 65 + r] = a.x;
        tile[(c4 * 4 + 1) * 65 + r] = a.y;
        tile[(c4 * 4 + 2) * 65 + r] = a.z;
        tile[(c4 * 4 + 3) * 65 + r] = a.w;
    }
    __syncthreads();
    #pragma unroll
    for (int v = 0; v < 4; ++v) {
        int flat = v * 256 + t;
        int il = flat >> 4, c4 = flat & 15;
        float4 a;
        a.x = tile[il * 65 + c4 * 4 + 0];
        a.y = tile[il * 65 + c4 * 4 + 1];
        a.z = tile[il * 65 + c4 * 4 + 2];
        a.w = tile[il * 65 + c4 * 4 + 3];
        int g = (i0 + il) * N_NODES + n0 + c4 * 4;
        *(float4*)&aggT[g] = a;
        float4 s;
        s.x = a.x / (1.0f + __expf(-a.x));
        s.y = a.y / (1.0f + __expf(-a.y));
        s.z = a.z / (1.0f + __expf(-a.z));
        s.w = a.w / (1.0f + __expf(-a.w));
        *(float4*)&siluT[g] = s;
    }
}

// ---------------- K2c: pack params pk[o][i] = (C/scale, C*trans/scale, MH_C*ww/C2, bw) ----------------
__global__ __launch_bounds__(256) void k_prep(const float* __restrict__ scale,
                                              const float* __restrict__ trans,
                                              const float* __restrict__ ww,
                                              const float* __restrict__ bw,
                                              float* __restrict__ pk) {
    int g = blockIdx.x * 256 + threadIdx.x;     // 0 .. 512*512-1
    float iv = 1.0f / scale[g];
    float4 p;
    p.x = iv * CSC;
    p.y = trans[g] * iv * CSC;
    p.z = ww[g] * WC2F;
    p.w = bw[g];
    ((float4*)pk)[g] = p;
}

// ---------------- K3: fused wavelet + base (6 pk + 2 exp per pair, conflict-free sP) ----------------
#define TN 64
#define TO 32
#define KI 16
#define TOP (TO + 1)
#define ZSPLIT 8
#define ZLEN (H_DIM / ZSPLIT)   // 64
__global__ __launch_bounds__(256, 4) void k_wavelet(const float* __restrict__ aggT,
                                                    const float* __restrict__ siluT,
                                                    const float* __restrict__ pk,
                                                    float* __restrict__ vbp) {
    __shared__ float sA[KI * TN];        // [i][n]
    __shared__ float sS[KI * TN];        // [i][n]
    __shared__ float4 sP4[KI * TOP];     // [i][o] padded (+1 float4) -> conflict-free reads

    const int t  = threadIdx.x;
    const int n0 = blockIdx.x * TN;
    const int o0 = blockIdx.y * TO;
    const int z0 = blockIdx.z * ZLEN;
    const int nl = (t & 15) * 4;
    const int ol = (t >> 4) * 2;

    v2f accw[2][2] = {};   // [oo][npair]
    v2f accb[2][2] = {};
    const v2f c2v = {(float)C2_D, (float)C2_D};

    for (int stg = 0; stg < ZLEN / KI; ++stg) {
        const int i0 = z0 + stg * KI;
        __syncthreads();
        // n-side: async global->LDS, dest = wave-uniform base + lane*16 (compatible)
        {
            int g = (i0 + (t >> 4)) * N_NODES + n0 + nl;
            __builtin_amdgcn_global_load_lds((gu32*)&aggT[g],  (lu32*)&sA[t * 4], 16, 0, 0);
            __builtin_amdgcn_global_load_lds((gu32*)&siluT[g], (lu32*)&sS[t * 4], 16, 0, 0);
        }
        // param side: stage transposed [ii][o]; global read coalesced, LDS write 2-way (free)
        #pragma unroll
        for (int j = 0; j < 2; ++j) {
            int u = j * 256 + t;             // 0..511
            int o = u >> 4, ii = u & 15;
            sP4[ii * TOP + o] = ((const float4*)pk)[(o0 + o) * H_DIM + i0 + ii];
        }
        __syncthreads();
        #pragma unroll 4
        for (int ii = 0; ii < KI; ++ii) {
            float4 a = *(const float4*)&sA[ii * TN + nl];
            float4 s = *(const float4*)&sS[ii * TN + nl];
            v2f a01 = {a.x, a.y}, a23 = {a.z, a.w};
            v2f s01 = {s.x, s.y}, s23 = {s.z, s.w};
            #pragma unroll
            for (int oo = 0; oo < 2; ++oo) {
                float4 p = sP4[ii * TOP + ol + oo];
                v2f iv2 = {p.x, p.x};
                v2f tf2 = {p.y, p.y};
                v2f w2  = {p.z, p.z};
                v2f b2  = {p.w, p.w};
                {
                    v2f y  = a01 * iv2 - tf2;       // y = C*xs
                    v2f y2 = y * y;
                    v2f e; e.x = EXP2NEG(y2.x); e.y = EXP2NEG(y2.y);  // exp2(-y2) = exp(-xs2/2)
                    v2f wm = w2 * (c2v - y2);       // (MH_C*ww/C2)*(C2-y2) = MH_C*ww*(1-xs2)
                    accw[oo][0] += wm * e;
                    accb[oo][0] += s01 * b2;
                }
                {
                    v2f y  = a23 * iv2 - tf2;
                    v2f y2 = y * y;
                    v2f e; e.x = EXP2NEG(y2.x); e.y = EXP2NEG(y2.y);
                    v2f wm = w2 * (c2v - y2);
                    accw[oo][1] += wm * e;
                    accb[oo][1] += s23 * b2;
                }
            }
        }
    }
    float* out = vbp + (size_t)blockIdx.z * (N_NODES * H_DIM);
    #pragma unroll
    for (int nn = 0; nn < 4; ++nn) {
        int pr = nn >> 1, cmu = nn & 1;
        float2 o2;
        o2.x = (cmu ? accw[0][pr].y : accw[0][pr].x) + (cmu ? accb[0][pr].y : accb[0][pr].x);
        o2.y = (cmu ? accw[1][pr].y : accw[1][pr].x) + (cmu ? accb[1][pr].y : accb[1][pr].x);
        *(float2*)&out[(n0 + nl + nn) * H_DIM + o0 + ol] = o2;
    }
}

// ---------------- K4: reduce partials -> vb, + column sum/sumsq ----------------
__global__ __launch_bounds__(256) void k_reduce(const float* __restrict__ vbp,
                                                float* __restrict__ vb,
                                                float* __restrict__ colsum,
                                                float* __restrict__ colsum2) {
    const int b = blockIdx.x;           // 64 blocks: 8 o-strips x 8 n-strips
    const int o0 = (b & 7) * 64;
    const int n0 = (b >> 3) * 128;
    const int t = threadIdx.x;
    const int oc = o0 + (t & 63);
    const int nsub = t >> 6;
    float s = 0.f, s2 = 0.f;
    for (int r = 0; r < 32; ++r) {
        int n = n0 + r * 4 + nsub;
        size_t idx = (size_t)n * H_DIM + oc;
        float v = 0.f;
        #pragma unroll
        for (int z = 0; z < ZSPLIT; ++z) v += vbp[z * (N_NODES * H_DIM) + idx];
        vb[idx] = v;
        s += v; s2 += v * v;
    }
    __shared__ float sh1[256], sh2[256];
    sh1[t] = s; sh2[t] = s2;
    __syncthreads();
    if (t < 64) {
        s  = sh1[t] + sh1[t + 64] + sh1[t + 128] + sh1[t + 192];
        s2 = sh2[t] + sh2[t + 64] + sh2[t + 128] + sh2[t + 192];
        unsafeAtomicAdd(&colsum[o0 + t], s);
        unsafeAtomicAdd(&colsum2[o0 + t], s2);
    }
}

// ---------------- K5: x column stats (coalesced, 64 blocks) ----------------
__global__ __launch_bounds__(256) void k_xstats(const float* __restrict__ x,
                                                float* __restrict__ xsum,
                                                float* __restrict__ xsum2) {
    const int n0 = blockIdx.x * 16;     // 64 blocks x 16 rows
    const int t = threadIdx.x;
    float s[4] = {}, s2[4] = {};
    for (int r = 0; r < 16; ++r) {
        #pragma unroll
        for (int ch = 0; ch < 4; ++ch) {
            float v = x[(n0 + r) * F_DIM + ch * 256 + t];
            s[ch] += v; s2[ch] += v * v;
        }
    }
    #pragma unroll
    for (int ch = 0; ch < 4; ++ch) {
        unsafeAtomicAdd(&xsum[ch * 256 + t], s[ch]);
        unsafeAtomicAdd(&xsum2[ch * 256 + t], s2[ch]);
    }
}

// ---------------- K6: finalize BN affine params + graph ranges (merged) ----------------
__global__ __launch_bounds__(256) void k_finalize(const float* __restrict__ colsum,
                                                  const float* __restrict__ colsum2,
                                                  const float* __restrict__ xsum,
                                                  const float* __restrict__ xsum2,
                                                  float* __restrict__ muv,
                                                  float* __restrict__ Sv,
                                                  float* __restrict__ mux,
                                                  float* __restrict__ Sx,
                                                  const int* __restrict__ batch,
                                                  int* __restrict__ gstart,
                                                  int* __restrict__ gcnt) {
    __shared__ int cnt_sh[B_GRAPHS];
    __shared__ int start_sh[B_GRAPHS];
    int t = threadIdx.x;
    if (t < B_GRAPHS) { cnt_sh[t] = 0; start_sh[t] = 0; }
    __syncthreads();
    for (int n = t; n < N_NODES; n += 256) {
        int b = batch[n];
        atomicAdd(&cnt_sh[b], 1);
        if (n == 0 || batch[n - 1] != b) start_sh[b] = n;
    }
    for (int c = t; c < FH_DIM; c += 256) {
        if (c < H_DIM) {
            float mu  = colsum[c] * (1.0f / N_NODES);
            float var = colsum2[c] * (1.0f / N_NODES) - mu * mu;
            if (var < 0.f) var = 0.f;
            float s1v = 1.0f / sqrtf(var + EPS);
            float v1  = var * s1v * s1v;
            float s2v = 1.0f / sqrtf(v1 + EPS);
            float v2  = v1 * s2v * s2v;
            float s3v = 1.0f / sqrtf(v2 + EPS);
            muv[c] = mu;
            Sv[c]  = s1v * s2v * s3v;
        } else {
            int xc = c - H_DIM;
            float mu  = xsum[xc] * (1.0f / N_NODES);
            float var = xsum2[xc] * (1.0f / N_NODES) - mu * mu;
            if (var < 0.f) var = 0.f;
            mux[xc] = mu;
            Sx[xc]  = 1.0f / sqrtf(var + EPS);
        }
    }
    __syncthreads();
    if (t < B_GRAPHS) { gstart[t] = start_sh[t]; gcnt[t] = cnt_sh[t]; }
}

// ---------------- K7: pooled[b,c] = (mean_b(col) - mu)*S  (16 x 6 blocks) ----------------
__global__ __launch_bounds__(256) void k_pool(const float* __restrict__ x,
                                              const float* __restrict__ vb,
                                              const int* __restrict__ gstart,
                                              const int* __restrict__ gcnt,
                                              const float* __restrict__ mux,
                                              const float* __restrict__ Sx,
                                              const float* __restrict__ muv,
                                              const float* __restrict__ Sv,
                                              float* __restrict__ pooled) {
    const int b = blockIdx.x;
    const int ch = blockIdx.y;          // 0..5: 4 x-chunks, 2 vb-chunks
    const int t = threadIdx.x;
    const int cnt = gcnt[b], st = gstart[b];
    float ic = (cnt > 0) ? 1.0f / (float)cnt : 0.f;
    float acc = 0.f;
    if (ch < 4) {
        const float* base = x + ch * 256 + t;
        for (int r = 0; r < cnt; ++r) acc += base[(size_t)(st + r) * F_DIM];
        int c = ch * 256 + t;
        pooled[b * FH_DIM + c] = (acc * ic - mux[c]) * Sx[c];
    } else {
        int chv = ch - 4;
        const float* base = vb + chv * 256 + t;
        for (int r = 0; r < cnt; ++r) acc += base[(size_t)(st + r) * H_DIM];
        int c = chv * 256 + t;
        pooled[b * FH_DIM + F_DIM + c] = (acc * ic - muv[c]) * Sv[c];
    }
}

// ---------------- K8: h1 = relu(pooled @ fc1_w^T + b1), float4 ----------------
__global__ __launch_bounds__(256) void k_fc1(const float* __restrict__ pooled,
                                             const float* __restrict__ w,
                                             const float* __restrict__ bias,
                                             float* __restrict__ h1) {
    int wid = (blockIdx.x * 256 + threadIdx.x) >> 6;   // 0..8191
    int lane = threadIdx.x & 63;
    int b = wid >> 9, o = wid & 511;
    const float4* pr = (const float4*)(pooled + b * FH_DIM);
    const float4* wr = (const float4*)(w + o * FH_DIM);
    float acc = 0.f;
    #pragma unroll
    for (int k = 0; k < 6; ++k) {                      // 6*64 = 384 = FH_DIM/4
        float4 a = pr[k * 64 + lane];
        float4 v = wr[k * 64 + lane];
        acc += a.x * v.x + a.y * v.y + a.z * v.z + a.w * v.w;
    }
    #pragma unroll
    for (int off = 32; off > 0; off >>= 1) acc += __shfl_down(acc, off);
    if (lane == 0) h1[b * H_DIM + o] = fmaxf(acc + bias[o], 0.f);
}

// ---------------- K9: out = h1 @ fc2_w^T + b2, float4 ----------------
__global__ __launch_bounds__(256) void k_fc2(const float* __restrict__ h1,
                                             const float* __restrict__ w,
                                             const float* __restrict__ bias,
                                             float* __restrict__ outp) {
    int wid = (blockIdx.x * 256 + threadIdx.x) >> 6;
    int lane = threadIdx.x & 63;
    if (wid >= B_GRAPHS * OUT_DIM) return;
    int b = wid / OUT_DIM, u = wid % OUT_DIM;
    const float4* hr = (const float4*)(h1 + b * H_DIM);
    const float4* wr = (const float4*)(w + u * H_DIM);
    float acc = 0.f;
    #pragma unroll
    for (int k = 0; k < 2; ++k) {                      // 2*64 = 128 = H_DIM/4
        float4 a = hr[k * 64 + lane];
        float4 v = wr[k * 64 + lane];
        acc += a.x * v.x + a.y * v.y + a.z * v.z + a.w * v.w;
    }
    #pragma unroll
    for (int off = 32; off > 0; off >>= 1) acc += __shfl_down(acc, off);
    if (lane == 0) outp[b * OUT_DIM + u] = acc + bias[u];
}

extern "C" void kernel_launch(void* const* d_in, const int* in_sizes, int n_in,
                              void* d_out, int out_size, void* d_ws, size_t ws_size,
                              hipStream_t stream) {
    const float* x       = (const float*)d_in[0];
    const float* w_att   = (const float*)d_in[1];
    const float* wk_scale= (const float*)d_in[2];
    const float* wk_trans= (const float*)d_in[3];
    const float* wk_wav  = (const float*)d_in[4];
    const float* wk_base = (const float*)d_in[5];
    const float* fc1_w   = (const float*)d_in[6];
    const float* fc1_b   = (const float*)d_in[7];
    const float* fc2_w   = (const float*)d_in[8];
    const float* fc2_b   = (const float*)d_in[9];
    const int*   eidx    = (const int*)d_in[10];
    const int*   batch   = (const int*)d_in[11];
    float* outp = (float*)d_out;

    float* ws = (float*)d_ws;
    const int NH = N_NODES * H_DIM;            // 524288
    float* h      = ws;                        // 524288
    float* agg    = h + NH;
    float* aggT   = agg + NH;
    float* siluT  = aggT + NH;
    float* pk     = siluT + NH;                // 1048576
    float* vbp    = pk + 4 * (H_DIM * H_DIM);  // 8*524288
    float* vb     = vbp + (size_t)ZSPLIT * NH;
    float* colsum = vb + NH;                   // 512
    float* colsum2= colsum + 512;              // 512
    float* xsum   = colsum2 + 512;             // 1024
    float* xsum2  = xsum + 1024;               // 1024
    int*   deg    = (int*)(xsum2 + 1024);      // 1024
    int*   estart = deg + N_NODES;
    int*   cursor = estart + N_NODES;
    int*   elist  = cursor + N_NODES;          // 32768
    float* muv    = (float*)(elist + E_EDGES); // 512
    float* Sv     = muv + 512;
    float* mux    = Sv + 512;                  // 1024
    float* Sx     = mux + 1024;
    int*   gstart = (int*)(Sx + 1024);
    int*   gcnt   = gstart + 16;
    float* pooled = (float*)(gcnt + 16);       // 24576
    float* h1     = pooled + B_GRAPHS * FH_DIM;// 8192

    const int* src = eidx;
    const int* dst = eidx + E_EDGES;

    // zero colsum/colsum2/xsum/xsum2 (3072) + deg (1024) — contiguous 4096 floats
    k_zero<<<16, 256, 0, stream>>>(colsum);
    k_h<<<NH / 256, 256, 0, stream>>>(x, w_att, h);
    k_hist<<<E_EDGES / 256, 256, 0, stream>>>(dst, deg);
    k_scan<<<1, N_NODES, 0, stream>>>(deg, estart, cursor);
    k_fill<<<E_EDGES / 256, 256, 0, stream>>>(src, dst, cursor, elist);
    k_prep<<<(H_DIM * H_DIM) / 256, 256, 0, stream>>>(wk_scale, wk_trans, wk_wav, wk_base, pk);
    k_xstats<<<64, 256, 0, stream>>>(x, xsum, xsum2);
    k_gather<<<N_NODES, 256, 0, stream>>>(h, estart, deg, elist, agg);
    {
        dim3 grid(N_NODES / 64, H_DIM / 64);
        k_transpose<<<grid, 256, 0, stream>>>(agg, aggT, siluT);
    }
    {
        dim3 grid(N_NODES / TN, H_DIM / TO, ZSPLIT);
        k_wavelet<<<grid, 256, 0, stream>>>(aggT, siluT, pk, vbp);
    }
    k_reduce<<<64, 256, 0, stream>>>(vbp, vb, colsum, colsum2);
    k_finalize<<<1, 256, 0, stream>>>(colsum, colsum2, xsum, xsum2, muv, Sv, mux, Sx,
                                      batch, gstart, gcnt);
    {
        dim3 grid(B_GRAPHS, 6);
        k_pool<<<grid, 256, 0, stream>>>(x, vb, gstart, gcnt, mux, Sx, muv, Sv, pooled);
    }
    k_fc1<<<(B_GRAPHS * H_DIM * 64) / 256, 256, 0, stream>>>(pooled, fc1_w, fc1_b, h1);
    k_fc2<<<(B_GRAPHS * OUT_DIM * 64 + 255) / 256, 256, 0, stream>>>(h1, fc2_w, fc2_b, outp);
}

// Round 2
// 195.246 us; speedup vs baseline: 1.2404x; 1.0997x over previous
//
#include <hip/hip_runtime.h>
#include <math.h>

// Problem constants (fixed by setup_inputs)
#define N_NODES 1024
#define F_DIM   1024
#define H_DIM   512
#define E_EDGES 32768
#define B_GRAPHS 16
#define OUT_DIM 10
#define FH_DIM  1536
#define EPS 1e-5f
#define MH_C_D 0.8673250705840776
#define C2_D   0.72134752044448170368   // 0.5*log2(e)
#define C2_F   ((float)C2_D)
#define CSC    0.84932180028801904272f  // sqrt(C2)
#define WC2F   ((float)(MH_C_D / C2_D)) // MH_C / C2
#define INV_SQRT2 0.70710678118654752440f

typedef float v2f __attribute__((ext_vector_type(2)));
typedef unsigned int u32;
typedef const __attribute__((address_space(1))) u32 gu32;
typedef __attribute__((address_space(3))) u32 lu32;

#if __has_builtin(__builtin_amdgcn_exp2f)
#define EXP2NEG(x) __builtin_amdgcn_exp2f(-(x))   // exp2(-x), neg is free src modifier
#else
#define EXP2NEG(x) __expf(-0.69314718055994530942f * (x))
#endif

// ---------------- KA: fused setup = k_h (2048 wg) + k_prep (1024 wg) + zero (16 wg) ----
// All parts independent; every consumer is in a later kernel launch.
__global__ __launch_bounds__(256) void k_setup(const float* __restrict__ x,
                                               const float* __restrict__ watt,
                                               float* __restrict__ h,
                                               const float* __restrict__ scale,
                                               const float* __restrict__ trans,
                                               const float* __restrict__ ww,
                                               const float* __restrict__ bw,
                                               float* __restrict__ pk,
                                               float* __restrict__ zbase) {
    const int bid = blockIdx.x;
    const int t = threadIdx.x;
    if (bid < 2048) {
        // Haar split + attention gate -> h
        int idx = bid * 256 + t;                      // 0 .. N*H-1
        float2 p = ((const float2*)x)[idx];
        float lo = (p.x + p.y) * INV_SQRT2;
        float hi = (p.x - p.y) * INV_SQRT2;
        float tt = lo * watt[0] + hi * watt[1];
        float sc = 1.0f / (1.0f + __expf(-tt));
        h[idx] = sc * lo + (1.0f - sc) * hi;
    } else if (bid < 3072) {
        // pack params pk[o][i] = (C/scale, C*trans/scale, MH_C*ww/C2, bw)
        int g = (bid - 2048) * 256 + t;               // 0 .. 512*512-1
        float iv = 1.0f / scale[g];
        float4 p;
        p.x = iv * CSC;
        p.y = trans[g] * iv * CSC;
        p.z = ww[g] * WC2F;
        p.w = bw[g];
        ((float4*)pk)[g] = p;
    } else {
        // zero colsum/colsum2/xsum/xsum2 (3072) + deg (1024) — contiguous 4096 floats
        zbase[(bid - 3072) * 256 + t] = 0.0f;
    }
}

// ---------------- KB: fused k_hist (128 wg) + k_xstats (64 wg) ----------------
__global__ __launch_bounds__(256) void k_hx(const int* __restrict__ dst,
                                            int* __restrict__ deg,
                                            const float* __restrict__ x,
                                            float* __restrict__ xsum,
                                            float* __restrict__ xsum2) {
    const int bid = blockIdx.x;
    const int t = threadIdx.x;
    if (bid < 128) {
        int e = bid * 256 + t;
        atomicAdd(&deg[dst[e]], 1);
    } else {
        const int n0 = (bid - 128) * 16;              // 64 blocks x 16 rows
        float s[4] = {}, s2[4] = {};
        for (int r = 0; r < 16; ++r) {
            #pragma unroll
            for (int ch = 0; ch < 4; ++ch) {
                float v = x[(n0 + r) * F_DIM + ch * 256 + t];
                s[ch] += v; s2[ch] += v * v;
            }
        }
        #pragma unroll
        for (int ch = 0; ch < 4; ++ch) {
            unsafeAtomicAdd(&xsum[ch * 256 + t], s[ch]);
            unsafeAtomicAdd(&xsum2[ch * 256 + t], s2[ch]);
        }
    }
}

// shfl-based scan: per-wave inclusive scan + cross-wave fixup
__global__ __launch_bounds__(1024) void k_scan(const int* __restrict__ deg,
                                               int* __restrict__ start,
                                               int* __restrict__ cursor) {
    __shared__ int wsum[16];
    int t = threadIdx.x;
    int lane = t & 63, wid = t >> 6;
    int v = deg[t];
    int x = v;
    #pragma unroll
    for (int off = 1; off < 64; off <<= 1) {
        int y = __shfl_up(x, off, 64);
        if (lane >= off) x += y;
    }
    if (lane == 63) wsum[wid] = x;
    __syncthreads();
    if (t < 16) {
        int w = wsum[t];
        int xs = w;
        #pragma unroll
        for (int off = 1; off < 16; off <<= 1) {
            int y = __shfl_up(xs, off, 64);
            if (t >= off) xs += y;
        }
        wsum[t] = xs - w;   // exclusive prefix of wave sums
    }
    __syncthreads();
    int excl = wsum[wid] + x - v;
    start[t] = excl;
    cursor[t] = excl;
}

__global__ __launch_bounds__(256) void k_fill(const int* __restrict__ src,
                                              const int* __restrict__ dst,
                                              int* __restrict__ cursor,
                                              int* __restrict__ elist) {
    int e = blockIdx.x * 256 + threadIdx.x;
    int slot = atomicAdd(&cursor[dst[e]], 1);
    elist[slot] = src[e];
}

// ---------------- K2: gather (atomic-free scatter-add), float2 + unroll4 ----------------
__global__ __launch_bounds__(256) void k_gather(const float* __restrict__ h,
                                                const int* __restrict__ start,
                                                const int* __restrict__ deg,
                                                const int* __restrict__ elist,
                                                float* __restrict__ agg) {
    int d = blockIdx.x;
    int t = threadIdx.x;
    int st = start[d], dg = deg[d];
    const float2* h2 = (const float2*)h;
    float2 a = h2[d * 256 + t];
    int k = 0;
    for (; k + 4 <= dg; k += 4) {
        int s0 = elist[st + k];
        int s1 = elist[st + k + 1];
        int s2 = elist[st + k + 2];
        int s3 = elist[st + k + 3];
        float2 v0 = h2[s0 * 256 + t];
        float2 v1 = h2[s1 * 256 + t];
        float2 v2 = h2[s2 * 256 + t];
        float2 v3 = h2[s3 * 256 + t];
        a.x += (v0.x + v1.x) + (v2.x + v3.x);
        a.y += (v0.y + v1.y) + (v2.y + v3.y);
    }
    for (; k < dg; ++k) {
        int s0 = elist[st + k];
        float2 v0 = h2[s0 * 256 + t];
        a.x += v0.x; a.y += v0.y;
    }
    ((float2*)agg)[d * 256 + t] = a;
}

// ---------------- K2b: transpose agg [n][i] -> aggT [i][n], + siluT ----------------
__global__ __launch_bounds__(256) void k_transpose(const float* __restrict__ agg,
                                                   float* __restrict__ aggT,
                                                   float* __restrict__ siluT) {
    __shared__ float tile[64 * 65];
    const int t = threadIdx.x;
    const int n0 = blockIdx.x * 64;
    const int i0 = blockIdx.y * 64;
    #pragma unroll
    for (int v = 0; v < 4; ++v) {
        int flat = v * 256 + t;
        int r = flat >> 4, c4 = flat & 15;
        float4 a = *(const float4*)&agg[(n0 + r) * H_DIM + i0 + c4 * 4];
        tile[(c4 * 4 + 0) * 65 + r] = a.x;
        tile[(c4 * 4 + 1) * 65 + r] = a.y;
        tile[(c4 * 4 + 2) * 65 + r] = a.z;
        tile[(c4 * 4 + 3) * 65 + r] = a.w;
    }
    __syncthreads();
    #pragma unroll
    for (int v = 0; v < 4; ++v) {
        int flat = v * 256 + t;
        int il = flat >> 4, c4 = flat & 15;
        float4 a;
        a.x = tile[il * 65 + c4 * 4 + 0];
        a.y = tile[il * 65 + c4 * 4 + 1];
        a.z = tile[il * 65 + c4 * 4 + 2];
        a.w = tile[il * 65 + c4 * 4 + 3];
        int g = (i0 + il) * N_NODES + n0 + c4 * 4;
        *(float4*)&aggT[g] = a;
        float4 s;
        s.x = a.x / (1.0f + __expf(-a.x));
        s.y = a.y / (1.0f + __expf(-a.y));
        s.z = a.z / (1.0f + __expf(-a.z));
        s.w = a.w / (1.0f + __expf(-a.w));
        *(float4*)&siluT[g] = s;
    }
}

// ---------------- K3: fused wavelet + base, 4n x 4o per thread ----------------
// Per element: y=fma, y2=mul, exp2(-y2), wm=fma(wc - w*y2), accw=fma, accb=fma
//   -> 5 VALU + 1 trans / element; 6 ds_read_b128 per 16 elements.
#define TN 64
#define TO 64
#define KI 16
#define TOP (TO + 1)
#define ZSPLIT 8
#define ZLEN (H_DIM / ZSPLIT)   // 64
__global__ __launch_bounds__(256) void k_wavelet(const float* __restrict__ aggT,
                                                 const float* __restrict__ siluT,
                                                 const float* __restrict__ pk,
                                                 float* __restrict__ vbp) {
    __shared__ float sA[KI * TN];        // 4KB  [i][n]
    __shared__ float sS[KI * TN];        // 4KB  [i][n]
    __shared__ float4 sP4[KI * TOP];     // 16.6KB [i][o] padded

    const int t  = threadIdx.x;
    const int n0 = blockIdx.x * TN;
    const int o0 = blockIdx.y * TO;
    const int z0 = blockIdx.z * ZLEN;
    const int nl = (t & 15) * 4;
    const int ol = (t >> 4) * 4;         // 16 groups * 4 = 64 o

    v2f accw[4][2] = {};   // [oo][npair]
    v2f accb[4][2] = {};

    for (int stg = 0; stg < ZLEN / KI; ++stg) {
        const int i0 = z0 + stg * KI;
        __syncthreads();
        // n-side: async global->LDS, dest lane-linear (wave-uniform base + lane*16)
        {
            int g = (i0 + (t >> 4)) * N_NODES + n0 + nl;
            __builtin_amdgcn_global_load_lds((gu32*)&aggT[g],  (lu32*)&sA[t * 4], 16, 0, 0);
            __builtin_amdgcn_global_load_lds((gu32*)&siluT[g], (lu32*)&sS[t * 4], 16, 0, 0);
        }
        // param side: stage transposed [ii][o]
        #pragma unroll
        for (int j = 0; j < 4; ++j) {
            int u = j * 256 + t;             // 0..1023
            int o = u >> 4, ii = u & 15;
            sP4[ii * TOP + o] = ((const float4*)pk)[(o0 + o) * H_DIM + i0 + ii];
        }
        __syncthreads();
        #pragma unroll 4
        for (int ii = 0; ii < KI; ++ii) {
            float4 a = *(const float4*)&sA[ii * TN + nl];
            float4 s = *(const float4*)&sS[ii * TN + nl];
            v2f a01 = {a.x, a.y}, a23 = {a.z, a.w};
            v2f s01 = {s.x, s.y}, s23 = {s.z, s.w};
            #pragma unroll
            for (int oo = 0; oo < 4; ++oo) {
                float4 p = sP4[ii * TOP + ol + oo];
                float wcs = p.z * C2_F;     // wc = MH_C*ww (amortized over 4 n)
                v2f iv2 = {p.x, p.x};
                v2f tf2 = {p.y, p.y};
                v2f w2  = {p.z, p.z};
                v2f wc2 = {wcs, wcs};
                v2f b2  = {p.w, p.w};
                {
                    v2f y  = a01 * iv2 - tf2;       // y = C*xs
                    v2f y2 = y * y;
                    v2f e; e.x = EXP2NEG(y2.x); e.y = EXP2NEG(y2.y);
                    v2f wm = wc2 - w2 * y2;         // MH_C*ww*(1-xs2)
                    accw[oo][0] += wm * e;
                    accb[oo][0] += s01 * b2;
                }
                {
                    v2f y  = a23 * iv2 - tf2;
                    v2f y2 = y * y;
                    v2f e; e.x = EXP2NEG(y2.x); e.y = EXP2NEG(y2.y);
                    v2f wm = wc2 - w2 * y2;
                    accw[oo][1] += wm * e;
                    accb[oo][1] += s23 * b2;
                }
            }
        }
    }
    float* out = vbp + (size_t)blockIdx.z * (N_NODES * H_DIM);
    #pragma unroll
    for (int nn = 0; nn < 4; ++nn) {
        int pr = nn >> 1, cmu = nn & 1;
        float4 o4;
        o4.x = cmu ? accw[0][pr].y + accb[0][pr].y : accw[0][pr].x + accb[0][pr].x;
        o4.y = cmu ? accw[1][pr].y + accb[1][pr].y : accw[1][pr].x + accb[1][pr].x;
        o4.z = cmu ? accw[2][pr].y + accb[2][pr].y : accw[2][pr].x + accb[2][pr].x;
        o4.w = cmu ? accw[3][pr].y + accb[3][pr].y : accw[3][pr].x + accb[3][pr].x;
        *(float4*)&out[(n0 + nl + nn) * H_DIM + o0 + ol] = o4;
    }
}

// ---------------- K4: reduce partials -> vb, + column sum/sumsq (128 blocks) ----------------
__global__ __launch_bounds__(256) void k_reduce(const float* __restrict__ vbp,
                                                float* __restrict__ vb,
                                                float* __restrict__ colsum,
                                                float* __restrict__ colsum2) {
    const int b = blockIdx.x;           // 128 blocks: 8 o-strips x 16 n-strips
    const int o0 = (b & 7) * 64;
    const int n0 = (b >> 3) * 64;
    const int t = threadIdx.x;
    const int oc = o0 + (t & 63);
    const int nsub = t >> 6;
    float s = 0.f, s2 = 0.f;
    for (int r = 0; r < 16; ++r) {
        int n = n0 + r * 4 + nsub;
        size_t idx = (size_t)n * H_DIM + oc;
        float v = 0.f;
        #pragma unroll
        for (int z = 0; z < ZSPLIT; ++z) v += vbp[z * (N_NODES * H_DIM) + idx];
        vb[idx] = v;
        s += v; s2 += v * v;
    }
    __shared__ float sh1[256], sh2[256];
    sh1[t] = s; sh2[t] = s2;
    __syncthreads();
    if (t < 64) {
        s  = sh1[t] + sh1[t + 64] + sh1[t + 128] + sh1[t + 192];
        s2 = sh2[t] + sh2[t + 64] + sh2[t + 128] + sh2[t + 192];
        unsafeAtomicAdd(&colsum[o0 + t], s);
        unsafeAtomicAdd(&colsum2[o0 + t], s2);
    }
}

// ---------------- K7: pool + inline BN-param + inline graph-range ----------------
// pooled[b,c] = (mean_b(col) - mu)*S ; mu,S recomputed per block (identical fp ops).
__global__ __launch_bounds__(256) void k_pool(const float* __restrict__ x,
                                              const float* __restrict__ vb,
                                              const int* __restrict__ batch,
                                              const float* __restrict__ colsum,
                                              const float* __restrict__ colsum2,
                                              const float* __restrict__ xsum,
                                              const float* __restrict__ xsum2,
                                              float* __restrict__ pooled) {
    const int b = blockIdx.x;
    const int ch = blockIdx.y;          // 0..5: 4 x-chunks, 2 vb-chunks
    const int t = threadIdx.x;

    // cooperative range find for graph b (batch is sorted)
    __shared__ int s_cnt[4];
    __shared__ int s_st;
    int c = 0;
    for (int n = t; n < N_NODES; n += 256) {
        int bb = batch[n];
        int pb = (n == 0) ? -1 : batch[n - 1];
        c += (bb == b) ? 1 : 0;
        if (bb == b && pb != b) s_st = n;   // at most one thread writes
    }
    #pragma unroll
    for (int off = 32; off > 0; off >>= 1) c += __shfl_down(c, off);
    if ((t & 63) == 0) s_cnt[t >> 6] = c;
    __syncthreads();
    int cnt = s_cnt[0] + s_cnt[1] + s_cnt[2] + s_cnt[3];
    int st = (cnt > 0) ? s_st : 0;
    float ic = (cnt > 0) ? 1.0f / (float)cnt : 0.f;

    float acc = 0.f;
    if (ch < 4) {
        int col = ch * 256 + t;
        float mu  = xsum[col] * (1.0f / N_NODES);
        float var = xsum2[col] * (1.0f / N_NODES) - mu * mu;
        if (var < 0.f) var = 0.f;
        float S = 1.0f / sqrtf(var + EPS);
        const float* base = x + col;
        for (int r = 0; r < cnt; ++r) acc += base[(size_t)(st + r) * F_DIM];
        pooled[b * FH_DIM + col] = (acc * ic - mu) * S;
    } else {
        int col = (ch - 4) * 256 + t;
        float mu  = colsum[col] * (1.0f / N_NODES);
        float var = colsum2[col] * (1.0f / N_NODES) - mu * mu;
        if (var < 0.f) var = 0.f;
        float s1v = 1.0f / sqrtf(var + EPS);
        float v1  = var * s1v * s1v;
        float s2v = 1.0f / sqrtf(v1 + EPS);
        float v2  = v1 * s2v * s2v;
        float s3v = 1.0f / sqrtf(v2 + EPS);
        float S = s1v * s2v * s3v;
        const float* base = vb + col;
        for (int r = 0; r < cnt; ++r) acc += base[(size_t)(st + r) * H_DIM];
        pooled[b * FH_DIM + F_DIM + col] = (acc * ic - mu) * S;
    }
}

// ---------------- K8: h1 = relu(pooled @ fc1_w^T + b1), float4 ----------------
__global__ __launch_bounds__(256) void k_fc1(const float* __restrict__ pooled,
                                             const float* __restrict__ w,
                                             const float* __restrict__ bias,
                                             float* __restrict__ h1) {
    int wid = (blockIdx.x * 256 + threadIdx.x) >> 6;   // 0..8191
    int lane = threadIdx.x & 63;
    int b = wid >> 9, o = wid & 511;
    const float4* pr = (const float4*)(pooled + b * FH_DIM);
    const float4* wr = (const float4*)(w + o * FH_DIM);
    float acc = 0.f;
    #pragma unroll
    for (int k = 0; k < 6; ++k) {                      // 6*64 = 384 = FH_DIM/4
        float4 a = pr[k * 64 + lane];
        float4 v = wr[k * 64 + lane];
        acc += a.x * v.x + a.y * v.y + a.z * v.z + a.w * v.w;
    }
    #pragma unroll
    for (int off = 32; off > 0; off >>= 1) acc += __shfl_down(acc, off);
    if (lane == 0) h1[b * H_DIM + o] = fmaxf(acc + bias[o], 0.f);
}

// ---------------- K9: out = h1 @ fc2_w^T + b2, float4 ----------------
__global__ __launch_bounds__(256) void k_fc2(const float* __restrict__ h1,
                                             const float* __restrict__ w,
                                             const float* __restrict__ bias,
                                             float* __restrict__ outp) {
    int wid = (blockIdx.x * 256 + threadIdx.x) >> 6;
    int lane = threadIdx.x & 63;
    if (wid >= B_GRAPHS * OUT_DIM) return;
    int b = wid / OUT_DIM, u = wid % OUT_DIM;
    const float4* hr = (const float4*)(h1 + b * H_DIM);
    const float4* wr = (const float4*)(w + u * H_DIM);
    float acc = 0.f;
    #pragma unroll
    for (int k = 0; k < 2; ++k) {                      // 2*64 = 128 = H_DIM/4
        float4 a = hr[k * 64 + lane];
        float4 v = wr[k * 64 + lane];
        acc += a.x * v.x + a.y * v.y + a.z * v.z + a.w * v.w;
    }
    #pragma unroll
    for (int off = 32; off > 0; off >>= 1) acc += __shfl_down(acc, off);
    if (lane == 0) outp[b * OUT_DIM + u] = acc + bias[u];
}

extern "C" void kernel_launch(void* const* d_in, const int* in_sizes, int n_in,
                              void* d_out, int out_size, void* d_ws, size_t ws_size,
                              hipStream_t stream) {
    const float* x       = (const float*)d_in[0];
    const float* w_att   = (const float*)d_in[1];
    const float* wk_scale= (const float*)d_in[2];
    const float* wk_trans= (const float*)d_in[3];
    const float* wk_wav  = (const float*)d_in[4];
    const float* wk_base = (const float*)d_in[5];
    const float* fc1_w   = (const float*)d_in[6];
    const float* fc1_b   = (const float*)d_in[7];
    const float* fc2_w   = (const float*)d_in[8];
    const float* fc2_b   = (const float*)d_in[9];
    const int*   eidx    = (const int*)d_in[10];
    const int*   batch   = (const int*)d_in[11];
    float* outp = (float*)d_out;

    float* ws = (float*)d_ws;
    const int NH = N_NODES * H_DIM;            // 524288
    float* h      = ws;                        // 524288
    float* agg    = h + NH;
    float* aggT   = agg + NH;
    float* siluT  = aggT + NH;
    float* pk     = siluT + NH;                // 1048576
    float* vbp    = pk + 4 * (H_DIM * H_DIM);  // 8*524288
    float* vb     = vbp + (size_t)ZSPLIT * NH;
    float* colsum = vb + NH;                   // 512
    float* colsum2= colsum + 512;              // 512
    float* xsum   = colsum2 + 512;             // 1024
    float* xsum2  = xsum + 1024;               // 1024
    int*   deg    = (int*)(xsum2 + 1024);      // 1024
    int*   estart = deg + N_NODES;
    int*   cursor = estart + N_NODES;
    int*   elist  = cursor + N_NODES;          // 32768
    float* pooled = (float*)(elist + E_EDGES); // 24576
    float* h1     = pooled + B_GRAPHS * FH_DIM;// 8192

    const int* src = eidx;
    const int* dst = eidx + E_EDGES;

    // 1. fused setup: h + pk + zero(colsum..deg, 4096 floats)
    k_setup<<<3088, 256, 0, stream>>>(x, w_att, h, wk_scale, wk_trans, wk_wav, wk_base,
                                      pk, colsum);
    // 2. fused hist + xstats
    k_hx<<<192, 256, 0, stream>>>(dst, deg, x, xsum, xsum2);
    // 3-5. scan, fill, gather
    k_scan<<<1, N_NODES, 0, stream>>>(deg, estart, cursor);
    k_fill<<<E_EDGES / 256, 256, 0, stream>>>(src, dst, cursor, elist);
    k_gather<<<N_NODES, 256, 0, stream>>>(h, estart, deg, elist, agg);
    // 6. transpose + silu
    {
        dim3 grid(N_NODES / 64, H_DIM / 64);
        k_transpose<<<grid, 256, 0, stream>>>(agg, aggT, siluT);
    }
    // 7. wavelet
    {
        dim3 grid(N_NODES / TN, H_DIM / TO, ZSPLIT);
        k_wavelet<<<grid, 256, 0, stream>>>(aggT, siluT, pk, vbp);
    }
    // 8. reduce partials + column stats
    k_reduce<<<128, 256, 0, stream>>>(vbp, vb, colsum, colsum2);
    // 9. pool (inline BN params + graph ranges)
    {
        dim3 grid(B_GRAPHS, 6);
        k_pool<<<grid, 256, 0, stream>>>(x, vb, batch, colsum, colsum2, xsum, xsum2, pooled);
    }
    // 10-11. fc1, fc2
    k_fc1<<<(B_GRAPHS * H_DIM * 64) / 256, 256, 0, stream>>>(pooled, fc1_w, fc1_b, h1);
    k_fc2<<<(B_GRAPHS * OUT_DIM * 64 + 255) / 256, 256, 0, stream>>>(h1, fc2_w, fc2_b, outp);
}